// Round 11
// baseline (62.905 us; speedup 1.0000x reference)
//
#include <hip/hip_runtime.h>
#include <math.h>

#define NQ 14
#define DEPTH 6
#define BLOCK 512
#define TS 528u   // bytes per 16x16 f16 tile: 512 data + 16 pad (132 dwords = 4 mod 32)
#define BUFSZ 33792u   // 64 * TS

typedef _Float16 h16;
typedef h16 h4 __attribute__((ext_vector_type(4)));
typedef float f4 __attribute__((ext_vector_type(4)));

// One block = one real component (comp=blockIdx&1) of item b=blockIdx>>1 (gates real).
// Bit p = 13 - qubit. Groups g0=[0-3] g1=[4-7] g2=[8-11] g3grp=[12,13,6,7] (I on 6,7).
// PAIRED passes per half-layer, both on mfma_f32_16x16x16f16:
//   MFMA1: A = state tile (rows=preserved axis, k=cols=g_P), B = G_P   -> D1
//   MFMA2: A = G_{P+1},  B = D1 REGISTERS VERBATIM (16x16x16 B-layout == D-layout)
// View X tiles (rows g1 x cols g0), T=bits[8..13], live in buffer A; view Y
// tiles (rows g3grp x cols g2), Ty=[g0(4),b4,b5], live in buffer B.
// addr = T*TS + row*32 + col*2. Wave tile maps: half A T=w*8+jt; half B
// Ty=(w&1)*8+jt+16*(w>>1); writes are b128 after the in-register jt-pair regroup.
// ROUND-11: PING-PONG buffers -> ONE barrier per half (reads consumed before
// the end-of-half barrier; next half's writes go to the other buffer). 26->15
// barriers. LDS: 2*33792 dyn + 13488 static = 81072 <= 81920 -> 2 blocks/CU kept.
// CZ(d-1): intra pairs + cross pairs (n&1)&&(k&8) baked into Bm. Layer-5 CZ
// skipped (probs sign-invariant).
__global__ __launch_bounds__(BLOCK, 6) void qsim_kernel(
    const float* __restrict__ x, const float* __restrict__ theta,
    const float* __restrict__ head_w, const float* __restrict__ head_b,
    float* __restrict__ out)   // (512,2) pre-zeroed, accumulated atomically
{
  extern __shared__ __align__(16) char sbuf[];   // 2 x 33792 B state buffers
  __shared__ __align__(16) h16 Bm[24][256];      // M[n*16+k] per (d,p), signs baked
  __shared__ float2 gtab[DEPTH * NQ];
  __shared__ float wA[2][16], wB[2][16], wC[2][4], wD[2][4], wE[2][4];
  __shared__ float xc[NQ], xs[NQ];
  __shared__ float redbuf[16];

  const int t = threadIdx.x;
  const int b = blockIdx.x >> 1;
  const int comp = blockIdx.x & 1;
  const int lane = t & 63;
  const int w = t >> 6;        // 8 waves
  const int m = lane & 15;
  const int kg = lane >> 4;

  char* const bufA = sbuf;            // X views
  char* const bufB = sbuf + BUFSZ;    // Y views

  // ---- phase 0: small tables ----
  if (t < DEPTH * NQ) {
    int d = t / NQ, bit = t - d * NQ;
    float hg = 0.5f * theta[d * NQ + (13 - bit)];
    gtab[t] = make_float2(cosf(hg), sinf(hg));
  } else if (t >= 128 && t < 160) {        // wA: bits 0-3
    int o = (t - 128) >> 4, v = t & 15; float s = 0.f;
    #pragma unroll
    for (int i = 0; i < 4; ++i) s += ((v >> i) & 1) ? -head_w[o*NQ+i] : head_w[o*NQ+i];
    wA[o][v] = s;
  } else if (t >= 160 && t < 192) {        // wB: bits 8-11
    int o = (t - 160) >> 4, v = t & 15; float s = 0.f;
    #pragma unroll
    for (int i = 0; i < 4; ++i) s += ((v >> i) & 1) ? -head_w[o*NQ+8+i] : head_w[o*NQ+8+i];
    wB[o][v] = s;
  } else if (t >= 192 && t < 200) {        // wC: bits 4,5
    int o = (t - 192) >> 2, v = t & 3;
    float s = ((v & 1) ? -head_w[o*NQ+4] : head_w[o*NQ+4])
            + ((v & 2) ? -head_w[o*NQ+5] : head_w[o*NQ+5]);
    wC[o][v] = s;
  } else if (t >= 200 && t < 208) {        // wD: bits 6,7
    int o = (t - 200) >> 2, v = t & 3;
    float s = ((v & 1) ? -head_w[o*NQ+6] : head_w[o*NQ+6])
            + ((v & 2) ? -head_w[o*NQ+7] : head_w[o*NQ+7]);
    wD[o][v] = s;
  } else if (t >= 208 && t < 216) {        // wE: bits 12,13
    int o = (t - 208) >> 2, v = t & 3;
    float s = ((v & 1) ? -head_w[o*NQ+12] : head_w[o*NQ+12])
            + ((v & 2) ? -head_w[o*NQ+13] : head_w[o*NQ+13]);
    wE[o][v] = s;
  } else if (t >= 224 && t < 224 + NQ) {
    int bit = t - 224;
    float h = 0.5f * x[b * NQ + (13 - bit)];
    xc[bit] = cosf(h); xs[bit] = sinf(h);
  }
  __syncthreads();

  // ---- phase 1a: Bm (rounds 5-10 arithmetic; all CZ signs baked) ----
  #pragma unroll
  for (int i = 0; i < 12; ++i) {
    int e = t + (i << 9);
    int pid = e >> 8, n = (e >> 4) & 15, k = e & 15;
    int d = pid >> 2, p = pid & 3;
    float val;
    if (p < 3) {
      val = 1.f;
      #pragma unroll
      for (int j = 0; j < 4; ++j) {
        float2 g = gtab[d * NQ + 4 * p + j];
        val *= ((n >> j) & 1) ? (((k >> j) & 1) ? g.x : g.y)
                              : (((k >> j) & 1) ? -g.y : g.x);
      }
      if (d >= 1) {
        int s = ((k & (k >> 1)) ^ ((k >> 1) & (k >> 2)) ^ ((k >> 2) & (k >> 3))) & 1;
        if (s) val = -val;
        if ((n & 1) && (k & 8)) val = -val;    // cross-pair sign (as rounds 5-10)
      }
    } else {          // g3grp = [12,13,6,7]: G12 x G13 x I x I
      if ((((n ^ k) >> 2) & 3) != 0) val = 0.f;
      else {
        float2 gA = gtab[d * NQ + 12], gB = gtab[d * NQ + 13];
        float f0 = (n & 1) ? ((k & 1) ? gA.x : gA.y) : ((k & 1) ? -gA.y : gA.x);
        float f1 = ((n >> 1) & 1) ? (((k >> 1) & 1) ? gB.x : gB.y)
                                  : (((k >> 1) & 1) ? -gB.y : gB.x);
        val = f0 * f1;
        if (d >= 1 && (k & (k >> 1) & 1)) val = -val;
      }
    }
    Bm[pid][n * 16 + k] = (h16)val;
  }

  // ---- phase 1b: init product state -> buffer A (view X) ----
  {
    float Mt = 1.f;
    #pragma unroll
    for (int p = 5; p < 14; ++p) Mt *= ((t >> (p - 5)) & 1) ? xs[p] : xc[p];
    const int pct = __popc((unsigned)t);
    uint32_t base = (uint32_t)(t >> 3) * TS + (uint32_t)((2 * t) & 15) * 32;
    #pragma unroll
    for (int g = 0; g < 4; ++g) {
      union { h16 h[8]; uint4 u; } pk;
      #pragma unroll
      for (int i = 0; i < 8; ++i) {
        int j = g * 8 + i;
        float mm = Mt;
        #pragma unroll
        for (int p = 0; p < 5; ++p) mm *= ((j >> p) & 1) ? xs[p] : xc[p];
        int e = (pct + __popc((unsigned)j)) & 3;   // (-i)^e
        float v = (comp == 0) ? ((e == 0) ? mm : ((e == 2) ? -mm : 0.f))
                              : ((e == 1) ? -mm : ((e == 3) ? mm : 0.f));
        pk.h[i] = (h16)v;
      }
      *(uint4*)(bufA + base + (uint32_t)(g >> 1) * 32 + (uint32_t)(g & 1) * 16) = pk.u;
    }
  }
  __syncthreads();

  // A-fragment (16x16x16): lane reads row m, cols kg*4..kg*4+3 -> b64, ALL lanes
  const uint32_t raA = (uint32_t)w * (8 * TS) + (uint32_t)m * 32 + (uint32_t)kg * 8;
  const uint32_t raB = (uint32_t)((w & 1) * 8 + 16 * (w >> 1)) * TS
                     + (uint32_t)m * 32 + (uint32_t)kg * 8;
  const uint32_t wbase = (uint32_t)m * TS + ((uint32_t)(w >> 1) + 4u * (uint32_t)kg) * 32
                       + (uint32_t)((w & 1) * 16);
  // gate fragment offset (both A- and B-side of x16): Bm[m*16 + kg*4 + i]
  const uint32_t gfo = (uint32_t)(m * 16 + kg * 4) * 2;

  float l0 = 0.f, l1 = 0.f;

  // paired half-layer: read src, MFMA1(state,gB) -> MFMA2(gA, D1-as-B), write dst.
  // ONE barrier at end of half (src != dst -> no read/overwrite hazard).
  auto do_half = [&](const char* src, char* dst, uint32_t rbase,
                     h4 gB, h4 gA, bool last) {
    h4 av[8];
    #pragma unroll
    for (int jt = 0; jt < 8; ++jt)
      av[jt] = *(const h4*)(src + rbase + (uint32_t)jt * TS);
    uint32_t qk[8][2];
    float bs0 = 0.f, bs1 = 0.f, we0[4], we1[4];
    if (last) {
      bs0 = wB[0][m] + wC[0][w >> 1] + wD[0][kg];
      bs1 = wB[1][m] + wC[1][w >> 1] + wD[1][kg];
      #pragma unroll
      for (int j = 0; j < 4; ++j) { we0[j] = wE[0][j]; we1[j] = wE[1][j]; }
    }
    #pragma unroll
    for (int jt = 0; jt < 8; ++jt) {
      f4 acc = {0.f, 0.f, 0.f, 0.f};
      acc = __builtin_amdgcn_mfma_f32_16x16x16f16(av[jt], gB, acc, 0, 0, 0);
      union { h16 h[4]; h4 v; uint32_t d[2]; } c1;
      c1.h[0] = (h16)acc[0]; c1.h[1] = (h16)acc[1];
      c1.h[2] = (h16)acc[2]; c1.h[3] = (h16)acc[3];
      f4 acc2 = {0.f, 0.f, 0.f, 0.f};
      acc2 = __builtin_amdgcn_mfma_f32_16x16x16f16(gA, c1.v, acc2, 0, 0, 0);
      if (!last) {
        union { h16 h[4]; uint32_t d[2]; } c2;
        c2.h[0] = (h16)acc2[0]; c2.h[1] = (h16)acc2[1];
        c2.h[2] = (h16)acc2[2]; c2.h[3] = (h16)acc2[3];
        qk[jt][0] = c2.d[0]; qk[jt][1] = c2.d[1];
      } else {
        float wt0 = wA[0][(w & 1) * 8 + jt], wt1 = wA[1][(w & 1) * 8 + jt];
        #pragma unroll
        for (int j = 0; j < 4; ++j) {
          float pr = acc2[j] * acc2[j];
          l0 += pr * (bs0 + wt0 + we0[j]);
          l1 += pr * (bs1 + wt1 + we1[j]);
        }
      }
    }
    if (!last) {
      #pragma unroll
      for (int r = 0; r < 4; ++r) {
        uint32_t o[4];
        #pragma unroll
        for (int q = 0; q < 4; ++q) {
          uint32_t lo = qk[2 * q][r >> 1], hi = qk[2 * q + 1][r >> 1];
          o[q] = (r & 1) ? ((lo >> 16) | (hi & 0xffff0000u))
                         : ((lo & 0xffffu) | (hi << 16));
        }
        *(uint4*)(dst + wbase + (uint32_t)r * (16 * TS)) =
            make_uint4(o[0], o[1], o[2], o[3]);
      }
      __syncthreads();   // writes visible; also orders next half's overwrite of src
    }
  };

  #pragma unroll 1
  for (int d = 0; d < DEPTH; ++d) {
    const char* base = (const char*)&Bm[d * 4 + 0][0];
    h4 g0f = *(const h4*)(base + gfo);
    h4 g1f = *(const h4*)(base + 512 + gfo);
    h4 g2f = *(const h4*)(base + 1024 + gfo);
    h4 g3f = *(const h4*)(base + 1536 + gfo);
    do_half(bufA, bufB, raA, g0f, g1f, false);           // passes 0,1: X -> Y
    do_half(bufB, bufA, raB, g2f, g3f, d == DEPTH - 1);  // passes 2,3: Y -> X
  }

  // ---- reduce partial logits, accumulate re/im via atomics ----
  #pragma unroll
  for (int off = 32; off > 0; off >>= 1) {
    l0 += __shfl_xor(l0, off);
    l1 += __shfl_xor(l1, off);
  }
  if (lane == 0) { redbuf[w] = l0; redbuf[8 + w] = l1; }
  __syncthreads();
  if (t == 0) {
    float s0 = 0.f, s1 = 0.f;
    #pragma unroll
    for (int i = 0; i < 8; ++i) { s0 += redbuf[i]; s1 += redbuf[8 + i]; }
    if (comp == 0) { s0 += head_b[0]; s1 += head_b[1]; }
    atomicAdd(&out[b * 2 + 0], s0);
    atomicAdd(&out[b * 2 + 1], s1);
  }
}

extern "C" void kernel_launch(void* const* d_in, const int* in_sizes, int n_in,
                              void* d_out, int out_size, void* d_ws, size_t ws_size,
                              hipStream_t stream) {
    const float* x      = (const float*)d_in[0];
    const float* theta  = (const float*)d_in[1];
    const float* head_w = (const float*)d_in[2];
    const float* head_b = (const float*)d_in[3];
    float* outp = (float*)d_out;
    const int batch = in_sizes[0] / NQ;  // 512
    hipMemsetAsync(outp, 0, (size_t)out_size * sizeof(float), stream);
    qsim_kernel<<<batch * 2, BLOCK, 2 * BUFSZ, stream>>>(x, theta, head_w, head_b, outp);
}

// Round 12
// 57.026 us; speedup vs baseline: 1.1031x; 1.1031x over previous
//
#include <hip/hip_runtime.h>
#include <math.h>

#define NQ 14
#define DEPTH 6
#define BLOCK 512
#define TS 528u       // bytes per 16x16 f16 tile: 512 data + 16 pad (132 dwords = 4 mod 32)
#define BUFSZ 33792u  // 64 * TS

typedef _Float16 h16;
typedef h16 h4 __attribute__((ext_vector_type(4)));
typedef float f4 __attribute__((ext_vector_type(4)));

// One block = one real component (comp=blockIdx&1) of item b=blockIdx>>1 (gates real).
// Bit p = 13 - qubit. Groups g0=[0-3] g1=[4-7] g2=[8-11] g3grp=[12,13,6,7] (I on 6,7).
// PAIRED passes per half-layer, both on mfma_f32_16x16x16f16:
//   MFMA1: A = state tile (rows=preserved axis, k=cols=g_P), B = G_P   -> D1
//   MFMA2: A = G_{P+1},  B = D1 REGISTERS VERBATIM (16x16x16 B-layout == D-layout)
// Single in-place state buffer (round-10 structure, 2 barriers/half). View X
// (rows g1 x cols g0, T=bits[8..13]) and view Y (rows g3grp x cols g2,
// Ty=[g0(4),b4,b5]) alternate in the same buffer. addr = T*TS + row*32 + col*2.
// ROUND-12: 4 blocks/CU. Static Bm[24][256] (12KB) -> per-layer double-buffered
// Bm2[2][4][256] (4KB), layer d+1 recomputed during layer d (no extra barriers;
// write->read separated by >=2 barriers, overwritten buffer last read a layer ago).
// Total LDS approx 39.1KB -> 4 blocks/CU = 32 waves/CU, zero dispatch tail
// (1024 blocks = 4 per CU exactly). launch_bounds(512,8) caps VGPR at 64.
// CZ(d-1): intra pairs + cross pairs (n&1)&&(k&8) baked into Bm. Layer-5 CZ
// skipped (probs sign-invariant).
__global__ __launch_bounds__(BLOCK, 8) void qsim_kernel(
    const float* __restrict__ x, const float* __restrict__ theta,
    const float* __restrict__ head_w, const float* __restrict__ head_b,
    float* __restrict__ out)   // (512,2) pre-zeroed, accumulated atomically
{
  extern __shared__ __align__(16) char sbuf[];   // 33792 B state buffer (in-place)
  __shared__ __align__(16) h16 Bm2[2][4][256];   // per-layer gate matrices, dbuf
  __shared__ float2 gtab[DEPTH * NQ];            // (cos,sin) theta/2 at [d*14+bit]
  __shared__ float wA[2][16], wB[2][16], wC[2][4], wD[2][4], wE[2][4];
  __shared__ float xc[NQ], xs[NQ];
  __shared__ float redbuf[16];

  const int t = threadIdx.x;
  const int b = blockIdx.x >> 1;
  const int comp = blockIdx.x & 1;
  const int lane = t & 63;
  const int w = t >> 6;        // 8 waves
  const int m = lane & 15;
  const int kg = lane >> 4;

  // ---- phase 0: small tables ----
  if (t < DEPTH * NQ) {
    int d = t / NQ, bit = t - d * NQ;
    float hg = 0.5f * theta[d * NQ + (13 - bit)];
    gtab[t] = make_float2(cosf(hg), sinf(hg));
  } else if (t >= 128 && t < 160) {        // wA: bits 0-3
    int o = (t - 128) >> 4, v = t & 15; float s = 0.f;
    #pragma unroll
    for (int i = 0; i < 4; ++i) s += ((v >> i) & 1) ? -head_w[o*NQ+i] : head_w[o*NQ+i];
    wA[o][v] = s;
  } else if (t >= 160 && t < 192) {        // wB: bits 8-11
    int o = (t - 160) >> 4, v = t & 15; float s = 0.f;
    #pragma unroll
    for (int i = 0; i < 4; ++i) s += ((v >> i) & 1) ? -head_w[o*NQ+8+i] : head_w[o*NQ+8+i];
    wB[o][v] = s;
  } else if (t >= 192 && t < 200) {        // wC: bits 4,5
    int o = (t - 192) >> 2, v = t & 3;
    float s = ((v & 1) ? -head_w[o*NQ+4] : head_w[o*NQ+4])
            + ((v & 2) ? -head_w[o*NQ+5] : head_w[o*NQ+5]);
    wC[o][v] = s;
  } else if (t >= 200 && t < 208) {        // wD: bits 6,7
    int o = (t - 200) >> 2, v = t & 3;
    float s = ((v & 1) ? -head_w[o*NQ+6] : head_w[o*NQ+6])
            + ((v & 2) ? -head_w[o*NQ+7] : head_w[o*NQ+7]);
    wD[o][v] = s;
  } else if (t >= 208 && t < 216) {        // wE: bits 12,13
    int o = (t - 208) >> 2, v = t & 3;
    float s = ((v & 1) ? -head_w[o*NQ+12] : head_w[o*NQ+12])
            + ((v & 2) ? -head_w[o*NQ+13] : head_w[o*NQ+13]);
    wE[o][v] = s;
  } else if (t >= 224 && t < 224 + NQ) {
    int bit = t - 224;
    float h = 0.5f * x[b * NQ + (13 - bit)];
    xc[bit] = cosf(h); xs[bit] = sinf(h);
  }
  __syncthreads();

  // per-layer Bm fill: 1024 entries, 2 per thread (arithmetic = rounds 5-11)
  auto fill_Bm = [&](int dd, h16* dst) {
    #pragma unroll
    for (int i = 0; i < 2; ++i) {
      int e = t + (i << 9);
      int p = e >> 8, n = (e >> 4) & 15, k = e & 15;
      float val;
      if (p < 3) {
        val = 1.f;
        #pragma unroll
        for (int j = 0; j < 4; ++j) {
          float2 g = gtab[dd * NQ + 4 * p + j];
          val *= ((n >> j) & 1) ? (((k >> j) & 1) ? g.x : g.y)
                                : (((k >> j) & 1) ? -g.y : g.x);
        }
        if (dd >= 1) {
          int s = ((k & (k >> 1)) ^ ((k >> 1) & (k >> 2)) ^ ((k >> 2) & (k >> 3))) & 1;
          if (s) val = -val;
          if ((n & 1) && (k & 8)) val = -val;    // cross-pair sign
        }
      } else {        // g3grp = [12,13,6,7]: G12 x G13 x I x I
        if ((((n ^ k) >> 2) & 3) != 0) val = 0.f;
        else {
          float2 gA = gtab[dd * NQ + 12], gB = gtab[dd * NQ + 13];
          float f0 = (n & 1) ? ((k & 1) ? gA.x : gA.y) : ((k & 1) ? -gA.y : gA.x);
          float f1 = ((n >> 1) & 1) ? (((k >> 1) & 1) ? gB.x : gB.y)
                                    : (((k >> 1) & 1) ? -gB.y : gB.x);
          val = f0 * f1;
          if (dd >= 1 && (k & (k >> 1) & 1)) val = -val;
        }
      }
      dst[p * 256 + n * 16 + k] = (h16)val;
    }
  };

  // ---- phase 1a: layer-0 matrices ----
  fill_Bm(0, &Bm2[0][0][0]);

  // ---- phase 1b: init product state -> view X ----
  {
    float Mt = 1.f;
    #pragma unroll
    for (int p = 5; p < 14; ++p) Mt *= ((t >> (p - 5)) & 1) ? xs[p] : xc[p];
    const int pct = __popc((unsigned)t);
    uint32_t base = (uint32_t)(t >> 3) * TS + (uint32_t)((2 * t) & 15) * 32;
    #pragma unroll
    for (int g = 0; g < 4; ++g) {
      union { h16 h[8]; uint4 u; } pk;
      #pragma unroll
      for (int i = 0; i < 8; ++i) {
        int j = g * 8 + i;
        float mm = Mt;
        #pragma unroll
        for (int p = 0; p < 5; ++p) mm *= ((j >> p) & 1) ? xs[p] : xc[p];
        int e = (pct + __popc((unsigned)j)) & 3;   // (-i)^e
        float v = (comp == 0) ? ((e == 0) ? mm : ((e == 2) ? -mm : 0.f))
                              : ((e == 1) ? -mm : ((e == 3) ? mm : 0.f));
        pk.h[i] = (h16)v;
      }
      *(uint4*)(sbuf + base + (uint32_t)(g >> 1) * 32 + (uint32_t)(g & 1) * 16) = pk.u;
    }
  }
  __syncthreads();

  // A-fragment (16x16x16): lane reads row m, cols kg*4..kg*4+3 -> b64, ALL lanes
  const uint32_t raA = (uint32_t)w * (8 * TS) + (uint32_t)m * 32 + (uint32_t)kg * 8;
  const uint32_t raB = (uint32_t)((w & 1) * 8 + 16 * (w >> 1)) * TS
                     + (uint32_t)m * 32 + (uint32_t)kg * 8;
  const uint32_t wbase = (uint32_t)m * TS + ((uint32_t)(w >> 1) + 4u * (uint32_t)kg) * 32
                       + (uint32_t)((w & 1) * 16);
  // gate fragment offset (both A- and B-side of x16): Bm[m*16 + kg*4 + i]
  const uint32_t gfo = (uint32_t)(m * 16 + kg * 4) * 2;

  float l0 = 0.f, l1 = 0.f;

  // paired half-layer: read, MFMA1(state,gB) -> MFMA2(gA, D1-as-B), write in-place.
  auto do_half = [&](uint32_t rbase, h4 gB, h4 gA, bool last) {
    h4 av[8];
    #pragma unroll
    for (int jt = 0; jt < 8; ++jt)
      av[jt] = *(const h4*)(sbuf + rbase + (uint32_t)jt * TS);
    uint32_t qk[8][2];
    float bs0 = 0.f, bs1 = 0.f, we0[4], we1[4];
    if (last) {
      bs0 = wB[0][m] + wC[0][w >> 1] + wD[0][kg];
      bs1 = wB[1][m] + wC[1][w >> 1] + wD[1][kg];
      #pragma unroll
      for (int j = 0; j < 4; ++j) { we0[j] = wE[0][j]; we1[j] = wE[1][j]; }
    }
    #pragma unroll
    for (int jt = 0; jt < 8; ++jt) {
      f4 acc = {0.f, 0.f, 0.f, 0.f};
      acc = __builtin_amdgcn_mfma_f32_16x16x16f16(av[jt], gB, acc, 0, 0, 0);
      union { h16 h[4]; h4 v; uint32_t d[2]; } c1;
      c1.h[0] = (h16)acc[0]; c1.h[1] = (h16)acc[1];
      c1.h[2] = (h16)acc[2]; c1.h[3] = (h16)acc[3];
      f4 acc2 = {0.f, 0.f, 0.f, 0.f};
      acc2 = __builtin_amdgcn_mfma_f32_16x16x16f16(gA, c1.v, acc2, 0, 0, 0);
      if (!last) {
        union { h16 h[4]; uint32_t d[2]; } c2;
        c2.h[0] = (h16)acc2[0]; c2.h[1] = (h16)acc2[1];
        c2.h[2] = (h16)acc2[2]; c2.h[3] = (h16)acc2[3];
        qk[jt][0] = c2.d[0]; qk[jt][1] = c2.d[1];
      } else {
        float wt0 = wA[0][(w & 1) * 8 + jt], wt1 = wA[1][(w & 1) * 8 + jt];
        #pragma unroll
        for (int j = 0; j < 4; ++j) {
          float pr = acc2[j] * acc2[j];
          l0 += pr * (bs0 + wt0 + we0[j]);
          l1 += pr * (bs1 + wt1 + we1[j]);
        }
      }
    }
    if (!last) {
      __syncthreads();   // all reads of this view done before overwrite
      #pragma unroll
      for (int r = 0; r < 4; ++r) {
        uint32_t o[4];
        #pragma unroll
        for (int q = 0; q < 4; ++q) {
          uint32_t lo = qk[2 * q][r >> 1], hi = qk[2 * q + 1][r >> 1];
          o[q] = (r & 1) ? ((lo >> 16) | (hi & 0xffff0000u))
                         : ((lo & 0xffffu) | (hi << 16));
        }
        *(uint4*)(sbuf + wbase + (uint32_t)r * (16 * TS)) =
            make_uint4(o[0], o[1], o[2], o[3]);
      }
      __syncthreads();   // writes visible before next half reads
    }
  };

  #pragma unroll 1
  for (int d = 0; d < DEPTH; ++d) {
    const char* base = (const char*)&Bm2[d & 1][0][0];
    h4 g0f = *(const h4*)(base + gfo);
    h4 g1f = *(const h4*)(base + 512 + gfo);
    h4 g2f = *(const h4*)(base + 1024 + gfo);
    h4 g3f = *(const h4*)(base + 1536 + gfo);
    if (d + 1 < DEPTH)   // overlap next layer's matrix build under this layer
      fill_Bm(d + 1, &Bm2[(d + 1) & 1][0][0]);
    do_half(raA, g0f, g1f, false);                 // passes 0,1 (g0 then g1)
    do_half(raB, g2f, g3f, d == DEPTH - 1);        // passes 2,3 (g2 then g3grp)
  }

  // ---- reduce partial logits, accumulate re/im via atomics ----
  #pragma unroll
  for (int off = 32; off > 0; off >>= 1) {
    l0 += __shfl_xor(l0, off);
    l1 += __shfl_xor(l1, off);
  }
  if (lane == 0) { redbuf[w] = l0; redbuf[8 + w] = l1; }
  __syncthreads();
  if (t == 0) {
    float s0 = 0.f, s1 = 0.f;
    #pragma unroll
    for (int i = 0; i < 8; ++i) { s0 += redbuf[i]; s1 += redbuf[8 + i]; }
    if (comp == 0) { s0 += head_b[0]; s1 += head_b[1]; }
    atomicAdd(&out[b * 2 + 0], s0);
    atomicAdd(&out[b * 2 + 1], s1);
  }
}

extern "C" void kernel_launch(void* const* d_in, const int* in_sizes, int n_in,
                              void* d_out, int out_size, void* d_ws, size_t ws_size,
                              hipStream_t stream) {
    const float* x      = (const float*)d_in[0];
    const float* theta  = (const float*)d_in[1];
    const float* head_w = (const float*)d_in[2];
    const float* head_b = (const float*)d_in[3];
    float* outp = (float*)d_out;
    const int batch = in_sizes[0] / NQ;  // 512
    hipMemsetAsync(outp, 0, (size_t)out_size * sizeof(float), stream);
    qsim_kernel<<<batch * 2, BLOCK, BUFSZ, stream>>>(x, theta, head_w, head_b, outp);
}

// Round 13
// 56.972 us; speedup vs baseline: 1.1041x; 1.0010x over previous
//
#include <hip/hip_runtime.h>
#include <math.h>

#define NQ 14
#define DEPTH 6
#define BLOCK 512
#define TS 528u       // bytes per 16x16 f16 tile: 512 data + 16 pad (132 dwords = 4 mod 32)
#define BUFSZ 33792u  // 64 * TS

typedef _Float16 h16;
typedef h16 h4 __attribute__((ext_vector_type(4)));
typedef float f4 __attribute__((ext_vector_type(4)));

// ============ pre-kernel: theta/head_w-derived constants -> d_ws ============
// BmG[24][256] h16 at ws+0 (12288 B); wtab[88] float at ws+12288.
// wtab layout: wA[o][v]=o*16+v (bits0-3), wB=32+o*16+v (bits8-11),
//              wC=64+o*4+v (b4,5), wD=72+o*4+v (b6,7), wE=80+o*4+v (b12,13).
__global__ __launch_bounds__(512, 1) void prep_kernel(
    const float* __restrict__ theta, const float* __restrict__ head_w,
    h16* __restrict__ BmG, float* __restrict__ wtab)
{
  __shared__ float2 gtab[DEPTH * NQ];
  const int t = threadIdx.x;
  if (t < DEPTH * NQ) {
    int d = t / NQ, bit = t - d * NQ;
    float hg = 0.5f * theta[d * NQ + (13 - bit)];
    gtab[t] = make_float2(cosf(hg), sinf(hg));
  }
  if (t < 88) {
    int o, v; float s = 0.f;
    if (t < 32) { o = t >> 4; v = t & 15;
      #pragma unroll
      for (int i = 0; i < 4; ++i) s += ((v>>i)&1) ? -head_w[o*NQ+i] : head_w[o*NQ+i];
    } else if (t < 64) { o = (t-32) >> 4; v = t & 15;
      #pragma unroll
      for (int i = 0; i < 4; ++i) s += ((v>>i)&1) ? -head_w[o*NQ+8+i] : head_w[o*NQ+8+i];
    } else if (t < 72) { o = (t-64) >> 2; v = t & 3;
      s = ((v&1)?-head_w[o*NQ+4]:head_w[o*NQ+4]) + ((v&2)?-head_w[o*NQ+5]:head_w[o*NQ+5]);
    } else if (t < 80) { o = (t-72) >> 2; v = t & 3;
      s = ((v&1)?-head_w[o*NQ+6]:head_w[o*NQ+6]) + ((v&2)?-head_w[o*NQ+7]:head_w[o*NQ+7]);
    } else { o = (t-80) >> 2; v = t & 3;
      s = ((v&1)?-head_w[o*NQ+12]:head_w[o*NQ+12]) + ((v&2)?-head_w[o*NQ+13]:head_w[o*NQ+13]);
    }
    wtab[t] = s;
  }
  __syncthreads();
  // Bm: 24 x 16 x 16, 12 entries per thread (arithmetic = rounds 5-12, signs baked)
  #pragma unroll
  for (int i = 0; i < 12; ++i) {
    int e = t + (i << 9);
    int pid = e >> 8, n = (e >> 4) & 15, k = e & 15;
    int d = pid >> 2, p = pid & 3;
    float val;
    if (p < 3) {
      val = 1.f;
      #pragma unroll
      for (int j = 0; j < 4; ++j) {
        float2 g = gtab[d * NQ + 4 * p + j];
        val *= ((n >> j) & 1) ? (((k >> j) & 1) ? g.x : g.y)
                              : (((k >> j) & 1) ? -g.y : g.x);
      }
      if (d >= 1) {
        int s = ((k & (k >> 1)) ^ ((k >> 1) & (k >> 2)) ^ ((k >> 2) & (k >> 3))) & 1;
        if (s) val = -val;
        if ((n & 1) && (k & 8)) val = -val;    // cross-pair CZ sign
      }
    } else {          // g3grp = [12,13,6,7]: G12 x G13 x I x I
      if ((((n ^ k) >> 2) & 3) != 0) val = 0.f;
      else {
        float2 gA = gtab[d * NQ + 12], gB = gtab[d * NQ + 13];
        float f0 = (n & 1) ? ((k & 1) ? gA.x : gA.y) : ((k & 1) ? -gA.y : gA.x);
        float f1 = ((n >> 1) & 1) ? (((k >> 1) & 1) ? gB.x : gB.y)
                                  : (((k >> 1) & 1) ? -gB.y : gB.x);
        val = f0 * f1;
        if (d >= 1 && (k & (k >> 1) & 1)) val = -val;    // intra pair (12,13)
      }
    }
    BmG[pid * 256 + n * 16 + k] = (h16)val;
  }
}

// ============ main kernel ============
// One block = one real component (comp=blockIdx&1) of item b=blockIdx>>1.
// Round-12 structure (single in-place buffer, paired x16-MFMA halves, register
// chaining D1->B2). ROUND-13: all theta-derived tables from d_ws (pre-kernel);
// gate fragments loaded from global per layer w/ 1-layer software prefetch.
// Static LDS ~600B; total ~34.4KB -> 4 blocks/CU (32 waves), zero tail.
__global__ __launch_bounds__(BLOCK, 8) void qsim_kernel(
    const float* __restrict__ x, const h16* __restrict__ BmG,
    const float* __restrict__ wtabG, const float* __restrict__ head_b,
    float* __restrict__ out)   // (512,2) pre-zeroed, accumulated atomically
{
  extern __shared__ __align__(16) char sbuf[];   // 33792 B state buffer (in-place)
  __shared__ float wtab[88];
  __shared__ float xc[NQ], xs[NQ];
  __shared__ float redbuf[16];

  const int t = threadIdx.x;
  const int b = blockIdx.x >> 1;
  const int comp = blockIdx.x & 1;
  const int lane = t & 63;
  const int w = t >> 6;        // 8 waves
  const int m = lane & 15;
  const int kg = lane >> 4;

  // ---- phase 0: load tables / per-item trig ----
  if (t < 88) wtab[t] = wtabG[t];
  if (t >= 128 && t < 128 + NQ) {
    int bit = t - 128;
    float h = 0.5f * x[b * NQ + (13 - bit)];
    xc[bit] = cosf(h); xs[bit] = sinf(h);
  }
  __syncthreads();

  // ---- init product state -> view X (E0 ordering, rounds 7-12) ----
  {
    float Mt = 1.f;
    #pragma unroll
    for (int p = 5; p < 14; ++p) Mt *= ((t >> (p - 5)) & 1) ? xs[p] : xc[p];
    const int pct = __popc((unsigned)t);
    uint32_t base = (uint32_t)(t >> 3) * TS + (uint32_t)((2 * t) & 15) * 32;
    #pragma unroll
    for (int g = 0; g < 4; ++g) {
      union { h16 h[8]; uint4 u; } pk;
      #pragma unroll
      for (int i = 0; i < 8; ++i) {
        int j = g * 8 + i;
        float mm = Mt;
        #pragma unroll
        for (int p = 0; p < 5; ++p) mm *= ((j >> p) & 1) ? xs[p] : xc[p];
        int e = (pct + __popc((unsigned)j)) & 3;   // (-i)^e
        float v = (comp == 0) ? ((e == 0) ? mm : ((e == 2) ? -mm : 0.f))
                              : ((e == 1) ? -mm : ((e == 3) ? mm : 0.f));
        pk.h[i] = (h16)v;
      }
      *(uint4*)(sbuf + base + (uint32_t)(g >> 1) * 32 + (uint32_t)(g & 1) * 16) = pk.u;
    }
  }
  __syncthreads();

  // A-fragment (16x16x16): lane reads row m, cols kg*4..kg*4+3 -> b64, ALL lanes
  const uint32_t raA = (uint32_t)w * (8 * TS) + (uint32_t)m * 32 + (uint32_t)kg * 8;
  const uint32_t raB = (uint32_t)((w & 1) * 8 + 16 * (w >> 1)) * TS
                     + (uint32_t)m * 32 + (uint32_t)kg * 8;
  const uint32_t wbase = (uint32_t)m * TS + ((uint32_t)(w >> 1) + 4u * (uint32_t)kg) * 32
                       + (uint32_t)((w & 1) * 16);

  float l0 = 0.f, l1 = 0.f;

  // paired half-layer: read, MFMA1(state,gB) -> MFMA2(gA, D1-as-B), write in-place.
  auto do_half = [&](uint32_t rbase, h4 gB, h4 gA, bool last) {
    h4 av[8];
    #pragma unroll
    for (int jt = 0; jt < 8; ++jt)
      av[jt] = *(const h4*)(sbuf + rbase + (uint32_t)jt * TS);
    uint32_t qk[8][2];
    float bs0 = 0.f, bs1 = 0.f;
    if (last) {
      bs0 = wtab[32 + m] + wtab[64 + (w >> 1)] + wtab[72 + kg];
      bs1 = wtab[48 + m] + wtab[68 + (w >> 1)] + wtab[76 + kg];
    }
    #pragma unroll
    for (int jt = 0; jt < 8; ++jt) {
      f4 acc = {0.f, 0.f, 0.f, 0.f};
      acc = __builtin_amdgcn_mfma_f32_16x16x16f16(av[jt], gB, acc, 0, 0, 0);
      union { h16 h[4]; h4 v; uint32_t d[2]; } c1;
      c1.h[0] = (h16)acc[0]; c1.h[1] = (h16)acc[1];
      c1.h[2] = (h16)acc[2]; c1.h[3] = (h16)acc[3];
      f4 acc2 = {0.f, 0.f, 0.f, 0.f};
      acc2 = __builtin_amdgcn_mfma_f32_16x16x16f16(gA, c1.v, acc2, 0, 0, 0);
      if (!last) {
        union { h16 h[4]; uint32_t d[2]; } c2;
        c2.h[0] = (h16)acc2[0]; c2.h[1] = (h16)acc2[1];
        c2.h[2] = (h16)acc2[2]; c2.h[3] = (h16)acc2[3];
        qk[jt][0] = c2.d[0]; qk[jt][1] = c2.d[1];
      } else {
        float wt0 = wtab[(w & 1) * 8 + jt], wt1 = wtab[16 + (w & 1) * 8 + jt];
        #pragma unroll
        for (int j = 0; j < 4; ++j) {
          float pr = acc2[j] * acc2[j];
          l0 += pr * (bs0 + wt0 + wtab[80 + j]);
          l1 += pr * (bs1 + wt1 + wtab[84 + j]);
        }
      }
    }
    if (!last) {
      __syncthreads();   // all reads of this view done before overwrite
      #pragma unroll
      for (int r = 0; r < 4; ++r) {
        uint32_t o[4];
        #pragma unroll
        for (int q = 0; q < 4; ++q) {
          uint32_t lo = qk[2 * q][r >> 1], hi = qk[2 * q + 1][r >> 1];
          o[q] = (r & 1) ? ((lo >> 16) | (hi & 0xffff0000u))
                         : ((lo & 0xffffu) | (hi << 16));
        }
        *(uint4*)(sbuf + wbase + (uint32_t)r * (16 * TS)) =
            make_uint4(o[0], o[1], o[2], o[3]);
      }
      __syncthreads();   // writes visible before next half reads
    }
  };

  // gate fragments from global, 1-layer software prefetch
  const h16* fb = BmG + (m * 16 + kg * 4);
  h4 c0 = *(const h4*)(fb +   0), c1 = *(const h4*)(fb + 256);
  h4 c2 = *(const h4*)(fb + 512), c3 = *(const h4*)(fb + 768);

  #pragma unroll 1
  for (int d = 0; d < DEPTH; ++d) {
    h4 n0 = {}, n1 = {}, n2 = {}, n3 = {};
    if (d + 1 < DEPTH) {
      const h16* nf = fb + (d + 1) * 1024;
      n0 = *(const h4*)(nf +   0); n1 = *(const h4*)(nf + 256);
      n2 = *(const h4*)(nf + 512); n3 = *(const h4*)(nf + 768);
    }
    do_half(raA, c0, c1, false);                 // passes 0,1 (g0 then g1)
    do_half(raB, c2, c3, d == DEPTH - 1);        // passes 2,3 (g2 then g3grp)
    c0 = n0; c1 = n1; c2 = n2; c3 = n3;
  }

  // ---- reduce partial logits, accumulate re/im via atomics ----
  #pragma unroll
  for (int off = 32; off > 0; off >>= 1) {
    l0 += __shfl_xor(l0, off);
    l1 += __shfl_xor(l1, off);
  }
  if (lane == 0) { redbuf[w] = l0; redbuf[8 + w] = l1; }
  __syncthreads();
  if (t == 0) {
    float s0 = 0.f, s1 = 0.f;
    #pragma unroll
    for (int i = 0; i < 8; ++i) { s0 += redbuf[i]; s1 += redbuf[8 + i]; }
    if (comp == 0) { s0 += head_b[0]; s1 += head_b[1]; }
    atomicAdd(&out[b * 2 + 0], s0);
    atomicAdd(&out[b * 2 + 1], s1);
  }
}

extern "C" void kernel_launch(void* const* d_in, const int* in_sizes, int n_in,
                              void* d_out, int out_size, void* d_ws, size_t ws_size,
                              hipStream_t stream) {
    const float* x      = (const float*)d_in[0];
    const float* theta  = (const float*)d_in[1];
    const float* head_w = (const float*)d_in[2];
    const float* head_b = (const float*)d_in[3];
    float* outp = (float*)d_out;
    h16*  BmG   = (h16*)d_ws;
    float* wtabG = (float*)((char*)d_ws + 12288);
    const int batch = in_sizes[0] / NQ;  // 512
    hipMemsetAsync(outp, 0, (size_t)out_size * sizeof(float), stream);
    prep_kernel<<<1, 512, 0, stream>>>(theta, head_w, BmG, wtabG);
    qsim_kernel<<<batch * 2, BLOCK, BUFSZ, stream>>>(x, BmG, wtabG, head_b, outp);
}

// Round 14
// 54.702 us; speedup vs baseline: 1.1499x; 1.0415x over previous
//
#include <hip/hip_runtime.h>
#include <math.h>

#define NQ 14
#define DEPTH 6
#define BLOCK 512
#define TS 528u       // bytes per 16x16 f16 tile: 512 data + 16 pad (132 dwords = 4 mod 32)
#define BUFSZ 33792u  // 64 * TS

typedef _Float16 h16;
typedef h16 h4 __attribute__((ext_vector_type(4)));
typedef float f4 __attribute__((ext_vector_type(4)));

// ============ pre-kernel: theta/head_w-derived constants -> d_ws ============
// BmG[24][256] h16 at ws+0 (12288 B); wtab[88] float at ws+12288.
// wtab layout: wA[o][v]=o*16+v (bits0-3), wB=32+o*16+v (bits8-11),
//              wC=64+o*4+v (b4,5), wD=72+o*4+v (b6,7), wE=80+o*4+v (b12,13).
__global__ __launch_bounds__(512, 1) void prep_kernel(
    const float* __restrict__ theta, const float* __restrict__ head_w,
    h16* __restrict__ BmG, float* __restrict__ wtab)
{
  __shared__ float2 gtab[DEPTH * NQ];
  const int t = threadIdx.x;
  if (t < DEPTH * NQ) {
    int d = t / NQ, bit = t - d * NQ;
    float hg = 0.5f * theta[d * NQ + (13 - bit)];
    gtab[t] = make_float2(cosf(hg), sinf(hg));
  }
  if (t < 88) {
    int o, v; float s = 0.f;
    if (t < 32) { o = t >> 4; v = t & 15;
      #pragma unroll
      for (int i = 0; i < 4; ++i) s += ((v>>i)&1) ? -head_w[o*NQ+i] : head_w[o*NQ+i];
    } else if (t < 64) { o = (t-32) >> 4; v = t & 15;
      #pragma unroll
      for (int i = 0; i < 4; ++i) s += ((v>>i)&1) ? -head_w[o*NQ+8+i] : head_w[o*NQ+8+i];
    } else if (t < 72) { o = (t-64) >> 2; v = t & 3;
      s = ((v&1)?-head_w[o*NQ+4]:head_w[o*NQ+4]) + ((v&2)?-head_w[o*NQ+5]:head_w[o*NQ+5]);
    } else if (t < 80) { o = (t-72) >> 2; v = t & 3;
      s = ((v&1)?-head_w[o*NQ+6]:head_w[o*NQ+6]) + ((v&2)?-head_w[o*NQ+7]:head_w[o*NQ+7]);
    } else { o = (t-80) >> 2; v = t & 3;
      s = ((v&1)?-head_w[o*NQ+12]:head_w[o*NQ+12]) + ((v&2)?-head_w[o*NQ+13]:head_w[o*NQ+13]);
    }
    wtab[t] = s;
  }
  __syncthreads();
  // Bm: 24 x 16 x 16, 12 entries per thread (arithmetic = rounds 5-13, signs baked)
  #pragma unroll
  for (int i = 0; i < 12; ++i) {
    int e = t + (i << 9);
    int pid = e >> 8, n = (e >> 4) & 15, k = e & 15;
    int d = pid >> 2, p = pid & 3;
    float val;
    if (p < 3) {
      val = 1.f;
      #pragma unroll
      for (int j = 0; j < 4; ++j) {
        float2 g = gtab[d * NQ + 4 * p + j];
        val *= ((n >> j) & 1) ? (((k >> j) & 1) ? g.x : g.y)
                              : (((k >> j) & 1) ? -g.y : g.x);
      }
      if (d >= 1) {
        int s = ((k & (k >> 1)) ^ ((k >> 1) & (k >> 2)) ^ ((k >> 2) & (k >> 3))) & 1;
        if (s) val = -val;
        if ((n & 1) && (k & 8)) val = -val;    // cross-pair CZ sign
      }
    } else {          // g3grp = [12,13,6,7]: G12 x G13 x I x I
      if ((((n ^ k) >> 2) & 3) != 0) val = 0.f;
      else {
        float2 gA = gtab[d * NQ + 12], gB = gtab[d * NQ + 13];
        float f0 = (n & 1) ? ((k & 1) ? gA.x : gA.y) : ((k & 1) ? -gA.y : gA.x);
        float f1 = ((n >> 1) & 1) ? (((k >> 1) & 1) ? gB.x : gB.y)
                                  : (((k >> 1) & 1) ? -gB.y : gB.x);
        val = f0 * f1;
        if (d >= 1 && (k & (k >> 1) & 1)) val = -val;    // intra pair (12,13)
      }
    }
    BmG[pid * 256 + n * 16 + k] = (h16)val;
  }
}

// ============ main kernel ============
// One block = one real component (comp=blockIdx&1) of item b=blockIdx>>1.
// Round-12 structure (single in-place buffer, paired x16-MFMA halves, register
// chaining D1->B2); theta-derived tables from d_ws (round-13 pre-kernel).
// ROUND-14: NO cross-layer prefetch (it spilled: 43MB scratch traffic in r13).
// Gate fragments loaded at layer top only (8B x4, L2-broadcast); live-range
// fits the 64-VGPR cap of launch_bounds(512,8) -> no scratch.
__global__ __launch_bounds__(BLOCK, 8) void qsim_kernel(
    const float* __restrict__ x, const h16* __restrict__ BmG,
    const float* __restrict__ wtabG, const float* __restrict__ head_b,
    float* __restrict__ out)   // (512,2) pre-zeroed, accumulated atomically
{
  extern __shared__ __align__(16) char sbuf[];   // 33792 B state buffer (in-place)
  __shared__ float wtab[88];
  __shared__ float xc[NQ], xs[NQ];
  __shared__ float redbuf[16];

  const int t = threadIdx.x;
  const int b = blockIdx.x >> 1;
  const int comp = blockIdx.x & 1;
  const int lane = t & 63;
  const int w = t >> 6;        // 8 waves
  const int m = lane & 15;
  const int kg = lane >> 4;

  // ---- phase 0: load tables / per-item trig ----
  if (t < 88) wtab[t] = wtabG[t];
  if (t >= 128 && t < 128 + NQ) {
    int bit = t - 128;
    float h = 0.5f * x[b * NQ + (13 - bit)];
    xc[bit] = cosf(h); xs[bit] = sinf(h);
  }
  __syncthreads();

  // ---- init product state -> view X (E0 ordering, rounds 7-13) ----
  {
    float Mt = 1.f;
    #pragma unroll
    for (int p = 5; p < 14; ++p) Mt *= ((t >> (p - 5)) & 1) ? xs[p] : xc[p];
    const int pct = __popc((unsigned)t);
    uint32_t base = (uint32_t)(t >> 3) * TS + (uint32_t)((2 * t) & 15) * 32;
    #pragma unroll
    for (int g = 0; g < 4; ++g) {
      union { h16 h[8]; uint4 u; } pk;
      #pragma unroll
      for (int i = 0; i < 8; ++i) {
        int j = g * 8 + i;
        float mm = Mt;
        #pragma unroll
        for (int p = 0; p < 5; ++p) mm *= ((j >> p) & 1) ? xs[p] : xc[p];
        int e = (pct + __popc((unsigned)j)) & 3;   // (-i)^e
        float v = (comp == 0) ? ((e == 0) ? mm : ((e == 2) ? -mm : 0.f))
                              : ((e == 1) ? -mm : ((e == 3) ? mm : 0.f));
        pk.h[i] = (h16)v;
      }
      *(uint4*)(sbuf + base + (uint32_t)(g >> 1) * 32 + (uint32_t)(g & 1) * 16) = pk.u;
    }
  }
  __syncthreads();

  // A-fragment (16x16x16): lane reads row m, cols kg*4..kg*4+3 -> b64, ALL lanes
  const uint32_t raA = (uint32_t)w * (8 * TS) + (uint32_t)m * 32 + (uint32_t)kg * 8;
  const uint32_t raB = (uint32_t)((w & 1) * 8 + 16 * (w >> 1)) * TS
                     + (uint32_t)m * 32 + (uint32_t)kg * 8;
  const uint32_t wbase = (uint32_t)m * TS + ((uint32_t)(w >> 1) + 4u * (uint32_t)kg) * 32
                       + (uint32_t)((w & 1) * 16);

  float l0 = 0.f, l1 = 0.f;

  // paired half-layer: read, MFMA1(state,gB) -> MFMA2(gA, D1-as-B), write in-place.
  auto do_half = [&](uint32_t rbase, h4 gB, h4 gA, bool last) {
    h4 av[8];
    #pragma unroll
    for (int jt = 0; jt < 8; ++jt)
      av[jt] = *(const h4*)(sbuf + rbase + (uint32_t)jt * TS);
    uint32_t qk[8][2];
    float bs0 = 0.f, bs1 = 0.f;
    if (last) {
      bs0 = wtab[32 + m] + wtab[64 + (w >> 1)] + wtab[72 + kg];
      bs1 = wtab[48 + m] + wtab[68 + (w >> 1)] + wtab[76 + kg];
    }
    #pragma unroll
    for (int jt = 0; jt < 8; ++jt) {
      f4 acc = {0.f, 0.f, 0.f, 0.f};
      acc = __builtin_amdgcn_mfma_f32_16x16x16f16(av[jt], gB, acc, 0, 0, 0);
      union { h16 h[4]; h4 v; uint32_t d[2]; } c1;
      c1.h[0] = (h16)acc[0]; c1.h[1] = (h16)acc[1];
      c1.h[2] = (h16)acc[2]; c1.h[3] = (h16)acc[3];
      f4 acc2 = {0.f, 0.f, 0.f, 0.f};
      acc2 = __builtin_amdgcn_mfma_f32_16x16x16f16(gA, c1.v, acc2, 0, 0, 0);
      if (!last) {
        union { h16 h[4]; uint32_t d[2]; } c2;
        c2.h[0] = (h16)acc2[0]; c2.h[1] = (h16)acc2[1];
        c2.h[2] = (h16)acc2[2]; c2.h[3] = (h16)acc2[3];
        qk[jt][0] = c2.d[0]; qk[jt][1] = c2.d[1];
      } else {
        float wt0 = wtab[(w & 1) * 8 + jt], wt1 = wtab[16 + (w & 1) * 8 + jt];
        #pragma unroll
        for (int j = 0; j < 4; ++j) {
          float pr = acc2[j] * acc2[j];
          l0 += pr * (bs0 + wt0 + wtab[80 + j]);
          l1 += pr * (bs1 + wt1 + wtab[84 + j]);
        }
      }
    }
    if (!last) {
      __syncthreads();   // all reads of this view done before overwrite
      #pragma unroll
      for (int r = 0; r < 4; ++r) {
        uint32_t o[4];
        #pragma unroll
        for (int q = 0; q < 4; ++q) {
          uint32_t lo = qk[2 * q][r >> 1], hi = qk[2 * q + 1][r >> 1];
          o[q] = (r & 1) ? ((lo >> 16) | (hi & 0xffff0000u))
                         : ((lo & 0xffffu) | (hi << 16));
        }
        *(uint4*)(sbuf + wbase + (uint32_t)r * (16 * TS)) =
            make_uint4(o[0], o[1], o[2], o[3]);
      }
      __syncthreads();   // writes visible before next half reads
    }
  };

  // gate fragments: loaded fresh at each layer top (L2-hot; no cross-layer
  // live range -> no spill)
  const h16* fb = BmG + (m * 16 + kg * 4);

  #pragma unroll 1
  for (int d = 0; d < DEPTH; ++d) {
    const h16* nf = fb + d * 1024;
    h4 g0f = *(const h4*)(nf +   0);
    h4 g1f = *(const h4*)(nf + 256);
    h4 g2f = *(const h4*)(nf + 512);
    h4 g3f = *(const h4*)(nf + 768);
    do_half(raA, g0f, g1f, false);                 // passes 0,1 (g0 then g1)
    do_half(raB, g2f, g3f, d == DEPTH - 1);        // passes 2,3 (g2 then g3grp)
  }

  // ---- reduce partial logits, accumulate re/im via atomics ----
  #pragma unroll
  for (int off = 32; off > 0; off >>= 1) {
    l0 += __shfl_xor(l0, off);
    l1 += __shfl_xor(l1, off);
  }
  if (lane == 0) { redbuf[w] = l0; redbuf[8 + w] = l1; }
  __syncthreads();
  if (t == 0) {
    float s0 = 0.f, s1 = 0.f;
    #pragma unroll
    for (int i = 0; i < 8; ++i) { s0 += redbuf[i]; s1 += redbuf[8 + i]; }
    if (comp == 0) { s0 += head_b[0]; s1 += head_b[1]; }
    atomicAdd(&out[b * 2 + 0], s0);
    atomicAdd(&out[b * 2 + 1], s1);
  }
}

extern "C" void kernel_launch(void* const* d_in, const int* in_sizes, int n_in,
                              void* d_out, int out_size, void* d_ws, size_t ws_size,
                              hipStream_t stream) {
    const float* x      = (const float*)d_in[0];
    const float* theta  = (const float*)d_in[1];
    const float* head_w = (const float*)d_in[2];
    const float* head_b = (const float*)d_in[3];
    float* outp = (float*)d_out;
    h16*  BmG   = (h16*)d_ws;
    float* wtabG = (float*)((char*)d_ws + 12288);
    const int batch = in_sizes[0] / NQ;  // 512
    hipMemsetAsync(outp, 0, (size_t)out_size * sizeof(float), stream);
    prep_kernel<<<1, 512, 0, stream>>>(theta, head_w, BmG, wtabG);
    qsim_kernel<<<batch * 2, BLOCK, BUFSZ, stream>>>(x, BmG, wtabG, head_b, outp);
}

// Round 15
// 52.004 us; speedup vs baseline: 1.2096x; 1.0519x over previous
//
#include <hip/hip_runtime.h>
#include <math.h>

#define NQ 14
#define DEPTH 6
#define BLOCK 512
#define TS 528u       // bytes per 16x16 f16 tile: 512 data + 16 pad (132 dwords = 4 mod 32)
#define BUFSZ 33792u  // 64 * TS

typedef _Float16 h16;
typedef h16 h4 __attribute__((ext_vector_type(4)));
typedef float f4 __attribute__((ext_vector_type(4)));

// ============ pre-kernel: constants -> d_ws, plus out zeroing ============
// BmG[24][256] h16 at ws+0 (12288 B); wtab[88] float at ws+12288.
__global__ __launch_bounds__(512, 1) void prep_kernel(
    const float* __restrict__ theta, const float* __restrict__ head_w,
    h16* __restrict__ BmG, float* __restrict__ wtab, float* __restrict__ outp)
{
  __shared__ float2 gtab[DEPTH * NQ];
  const int t = threadIdx.x;
  if (t < 256)   // zero out[1024] (replaces the separate hipMemsetAsync dispatch)
    *(float4*)(outp + 4 * t) = make_float4(0.f, 0.f, 0.f, 0.f);
  if (t < DEPTH * NQ) {
    int d = t / NQ, bit = t - d * NQ;
    float hg = 0.5f * theta[d * NQ + (13 - bit)];
    gtab[t] = make_float2(cosf(hg), sinf(hg));
  }
  if (t < 88) {
    int o, v; float s = 0.f;
    if (t < 32) { o = t >> 4; v = t & 15;
      #pragma unroll
      for (int i = 0; i < 4; ++i) s += ((v>>i)&1) ? -head_w[o*NQ+i] : head_w[o*NQ+i];
    } else if (t < 64) { o = (t-32) >> 4; v = t & 15;
      #pragma unroll
      for (int i = 0; i < 4; ++i) s += ((v>>i)&1) ? -head_w[o*NQ+8+i] : head_w[o*NQ+8+i];
    } else if (t < 72) { o = (t-64) >> 2; v = t & 3;
      s = ((v&1)?-head_w[o*NQ+4]:head_w[o*NQ+4]) + ((v&2)?-head_w[o*NQ+5]:head_w[o*NQ+5]);
    } else if (t < 80) { o = (t-72) >> 2; v = t & 3;
      s = ((v&1)?-head_w[o*NQ+6]:head_w[o*NQ+6]) + ((v&2)?-head_w[o*NQ+7]:head_w[o*NQ+7]);
    } else { o = (t-80) >> 2; v = t & 3;
      s = ((v&1)?-head_w[o*NQ+12]:head_w[o*NQ+12]) + ((v&2)?-head_w[o*NQ+13]:head_w[o*NQ+13]);
    }
    wtab[t] = s;
  }
  __syncthreads();
  // Bm: 24 x 16 x 16 (arithmetic = rounds 5-14, CZ signs baked)
  #pragma unroll
  for (int i = 0; i < 12; ++i) {
    int e = t + (i << 9);
    int pid = e >> 8, n = (e >> 4) & 15, k = e & 15;
    int d = pid >> 2, p = pid & 3;
    float val;
    if (p < 3) {
      val = 1.f;
      #pragma unroll
      for (int j = 0; j < 4; ++j) {
        float2 g = gtab[d * NQ + 4 * p + j];
        val *= ((n >> j) & 1) ? (((k >> j) & 1) ? g.x : g.y)
                              : (((k >> j) & 1) ? -g.y : g.x);
      }
      if (d >= 1) {
        int s = ((k & (k >> 1)) ^ ((k >> 1) & (k >> 2)) ^ ((k >> 2) & (k >> 3))) & 1;
        if (s) val = -val;
        if ((n & 1) && (k & 8)) val = -val;    // cross-pair CZ sign
      }
    } else {          // g3grp = [12,13,6,7]: G12 x G13 x I x I
      if ((((n ^ k) >> 2) & 3) != 0) val = 0.f;
      else {
        float2 gA = gtab[d * NQ + 12], gB = gtab[d * NQ + 13];
        float f0 = (n & 1) ? ((k & 1) ? gA.x : gA.y) : ((k & 1) ? -gA.y : gA.x);
        float f1 = ((n >> 1) & 1) ? (((k >> 1) & 1) ? gB.x : gB.y)
                                  : (((k >> 1) & 1) ? -gB.y : gB.x);
        val = f0 * f1;
        if (d >= 1 && (k & (k >> 1) & 1)) val = -val;    // intra pair (12,13)
      }
    }
    BmG[pid * 256 + n * 16 + k] = (h16)val;
  }
}

// ============ main kernel ============
// One block = one real component (comp=blockIdx&1) of item b=blockIdx>>1.
// Round-14 structure (single in-place buffer, paired x16-MFMA halves, register
// chaining D1->B2, gates from d_ws). ROUND-15: init computed DIRECTLY into the
// layer-0 half-A register fragments (identical f32 mult order -> bit-identical
// values); deletes init LDS write + layer-0 read + 2 barriers. memset dispatch
// folded into prep_kernel.
__global__ __launch_bounds__(BLOCK, 8) void qsim_kernel(
    const float* __restrict__ x, const h16* __restrict__ BmG,
    const float* __restrict__ wtabG, const float* __restrict__ head_b,
    float* __restrict__ out)   // (512,2) zeroed by prep, accumulated atomically
{
  extern __shared__ __align__(16) char sbuf[];   // 33792 B state buffer (in-place)
  __shared__ float wtab[88];
  __shared__ float xc[NQ], xs[NQ];
  __shared__ float redbuf[16];

  const int t = threadIdx.x;
  const int b = blockIdx.x >> 1;
  const int comp = blockIdx.x & 1;
  const int lane = t & 63;
  const int w = t >> 6;        // 8 waves
  const int m = lane & 15;
  const int kg = lane >> 4;

  // ---- phase 0: load tables / per-item trig ----
  if (t < 88) wtab[t] = wtabG[t];
  if (t >= 128 && t < 128 + NQ) {
    int bit = t - 128;
    float h = 0.5f * x[b * NQ + (13 - bit)];
    xc[bit] = cosf(h); xs[bit] = sinf(h);
  }
  __syncthreads();

  // ---- init product state directly into layer-0 half-A fragments ----
  // amp k = col | (m&1)<<4 | (m>>1)<<5 | jt<<8 | w<<11, col = kg*4+i.
  // Multiplication chain order identical to rounds 7-14 init (bit-identical).
  h4 av[8];
  {
    const int mh = m >> 1;
    float t57 = 1.f;
    #pragma unroll
    for (int p = 5; p < 8; ++p) t57 *= ((mh >> (p - 5)) & 1) ? xs[p] : xc[p];
    const int pcb = __popc((unsigned)mh) + __popc((unsigned)w);
    #pragma unroll
    for (int jt = 0; jt < 8; ++jt) {
      float m13 = t57;
      #pragma unroll
      for (int p = 8; p < 11; ++p) m13 *= ((jt >> (p - 8)) & 1) ? xs[p] : xc[p];
      #pragma unroll
      for (int p = 11; p < 14; ++p) m13 *= ((w >> (p - 11)) & 1) ? xs[p] : xc[p];
      const int pch = pcb + __popc((unsigned)jt);
      union { h16 h[4]; h4 v; } fa;
      #pragma unroll
      for (int i = 0; i < 4; ++i) {
        const int col = kg * 4 + i;
        float mm = m13;
        #pragma unroll
        for (int p = 0; p < 4; ++p) mm *= ((col >> p) & 1) ? xs[p] : xc[p];
        const int b4 = m & 1;
        mm *= b4 ? xs[4] : xc[4];
        int e = (pch + __popc((unsigned)col) + b4) & 3;   // (-i)^e
        float v = (comp == 0) ? ((e == 0) ? mm : ((e == 2) ? -mm : 0.f))
                              : ((e == 1) ? -mm : ((e == 3) ? mm : 0.f));
        fa.h[i] = (h16)v;
      }
      av[jt] = fa.v;
    }
  }

  // A-fragment (16x16x16): lane reads row m, cols kg*4..kg*4+3 -> b64, ALL lanes
  const uint32_t raA = (uint32_t)w * (8 * TS) + (uint32_t)m * 32 + (uint32_t)kg * 8;
  const uint32_t raB = (uint32_t)((w & 1) * 8 + 16 * (w >> 1)) * TS
                     + (uint32_t)m * 32 + (uint32_t)kg * 8;
  const uint32_t wbase = (uint32_t)m * TS + ((uint32_t)(w >> 1) + 4u * (uint32_t)kg) * 32
                       + (uint32_t)((w & 1) * 16);

  float l0 = 0.f, l1 = 0.f;

  auto load_av = [&](uint32_t rbase) {
    #pragma unroll
    for (int jt = 0; jt < 8; ++jt)
      av[jt] = *(const h4*)(sbuf + rbase + (uint32_t)jt * TS);
  };

  // paired half-layer: MFMA1(state,gB) -> MFMA2(gA, D1-as-B), write in-place.
  // first=true (d0 half A): no prior LDS reads -> skip the WAR barrier.
  auto core = [&](h4 gB, h4 gA, bool last, bool first) {
    uint32_t qk[8][2];
    float bs0 = 0.f, bs1 = 0.f;
    if (last) {
      bs0 = wtab[32 + m] + wtab[64 + (w >> 1)] + wtab[72 + kg];
      bs1 = wtab[48 + m] + wtab[68 + (w >> 1)] + wtab[76 + kg];
    }
    #pragma unroll
    for (int jt = 0; jt < 8; ++jt) {
      f4 acc = {0.f, 0.f, 0.f, 0.f};
      acc = __builtin_amdgcn_mfma_f32_16x16x16f16(av[jt], gB, acc, 0, 0, 0);
      union { h16 h[4]; h4 v; uint32_t d[2]; } c1;
      c1.h[0] = (h16)acc[0]; c1.h[1] = (h16)acc[1];
      c1.h[2] = (h16)acc[2]; c1.h[3] = (h16)acc[3];
      f4 acc2 = {0.f, 0.f, 0.f, 0.f};
      acc2 = __builtin_amdgcn_mfma_f32_16x16x16f16(gA, c1.v, acc2, 0, 0, 0);
      if (!last) {
        union { h16 h[4]; uint32_t d[2]; } c2;
        c2.h[0] = (h16)acc2[0]; c2.h[1] = (h16)acc2[1];
        c2.h[2] = (h16)acc2[2]; c2.h[3] = (h16)acc2[3];
        qk[jt][0] = c2.d[0]; qk[jt][1] = c2.d[1];
      } else {
        float wt0 = wtab[(w & 1) * 8 + jt], wt1 = wtab[16 + (w & 1) * 8 + jt];
        #pragma unroll
        for (int j = 0; j < 4; ++j) {
          float pr = acc2[j] * acc2[j];
          l0 += pr * (bs0 + wt0 + wtab[80 + j]);
          l1 += pr * (bs1 + wt1 + wtab[84 + j]);
        }
      }
    }
    if (!last) {
      if (!first) __syncthreads();   // all reads of this view done before overwrite
      #pragma unroll
      for (int r = 0; r < 4; ++r) {
        uint32_t o[4];
        #pragma unroll
        for (int q = 0; q < 4; ++q) {
          uint32_t lo = qk[2 * q][r >> 1], hi = qk[2 * q + 1][r >> 1];
          o[q] = (r & 1) ? ((lo >> 16) | (hi & 0xffff0000u))
                         : ((lo & 0xffffu) | (hi << 16));
        }
        *(uint4*)(sbuf + wbase + (uint32_t)r * (16 * TS)) =
            make_uint4(o[0], o[1], o[2], o[3]);
      }
      __syncthreads();   // writes visible before next half reads
    }
  };

  const h16* fb = BmG + (m * 16 + kg * 4);

  #pragma unroll 1
  for (int d = 0; d < DEPTH; ++d) {
    const h16* nf = fb + d * 1024;
    h4 g0f = *(const h4*)(nf +   0);
    h4 g1f = *(const h4*)(nf + 256);
    h4 g2f = *(const h4*)(nf + 512);
    h4 g3f = *(const h4*)(nf + 768);
    if (d > 0) load_av(raA);
    core(g0f, g1f, false, d == 0);                 // passes 0,1 (g0 then g1)
    load_av(raB);
    core(g2f, g3f, d == DEPTH - 1, false);         // passes 2,3 (g2 then g3grp)
  }

  // ---- reduce partial logits, accumulate re/im via atomics ----
  #pragma unroll
  for (int off = 32; off > 0; off >>= 1) {
    l0 += __shfl_xor(l0, off);
    l1 += __shfl_xor(l1, off);
  }
  if (lane == 0) { redbuf[w] = l0; redbuf[8 + w] = l1; }
  __syncthreads();
  if (t == 0) {
    float s0 = 0.f, s1 = 0.f;
    #pragma unroll
    for (int i = 0; i < 8; ++i) { s0 += redbuf[i]; s1 += redbuf[8 + i]; }
    if (comp == 0) { s0 += head_b[0]; s1 += head_b[1]; }
    atomicAdd(&out[b * 2 + 0], s0);
    atomicAdd(&out[b * 2 + 1], s1);
  }
}

extern "C" void kernel_launch(void* const* d_in, const int* in_sizes, int n_in,
                              void* d_out, int out_size, void* d_ws, size_t ws_size,
                              hipStream_t stream) {
    const float* x      = (const float*)d_in[0];
    const float* theta  = (const float*)d_in[1];
    const float* head_w = (const float*)d_in[2];
    const float* head_b = (const float*)d_in[3];
    float* outp = (float*)d_out;
    h16*  BmG   = (h16*)d_ws;
    float* wtabG = (float*)((char*)d_ws + 12288);
    const int batch = in_sizes[0] / NQ;  // 512
    prep_kernel<<<1, 512, 0, stream>>>(theta, head_w, BmG, wtabG, outp);
    qsim_kernel<<<batch * 2, BLOCK, BUFSZ, stream>>>(x, BmG, wtabG, head_b, outp);
}

// Round 16
// 51.578 us; speedup vs baseline: 1.2196x; 1.0083x over previous
//
#include <hip/hip_runtime.h>
#include <math.h>

#define NQ 14
#define DEPTH 6
#define BLOCK 512
#define TS 528u       // bytes per 16x16 f16 tile: 512 data + 16 pad (132 dwords = 4 mod 32)
#define BUFSZ 33792u  // 64 * TS

typedef _Float16 h16;
typedef h16 h4 __attribute__((ext_vector_type(4)));
typedef float f4 __attribute__((ext_vector_type(4)));

// WAR barrier: no waitcnt needed (all prior ds_reads already consumed by MFMA);
// crucially does NOT drain vmcnt -> per-layer global gate loads stay in flight.
#define BAR_WAR() asm volatile("s_barrier" ::: "memory")
// Publish barrier: drain LDS writes only (lgkmcnt), not vmcnt.
#define BAR_PUB() asm volatile("s_waitcnt lgkmcnt(0)\n\ts_barrier" ::: "memory")

// ============ pre-kernel: constants -> d_ws, plus out zeroing ============
// BmG[24][256] h16 at ws+0 (12288 B); wtab[88] float at ws+12288.
__global__ __launch_bounds__(512, 1) void prep_kernel(
    const float* __restrict__ theta, const float* __restrict__ head_w,
    h16* __restrict__ BmG, float* __restrict__ wtab, float* __restrict__ outp)
{
  __shared__ float2 gtab[DEPTH * NQ];
  const int t = threadIdx.x;
  if (t < 256)   // zero out[1024] (replaces the separate hipMemsetAsync dispatch)
    *(float4*)(outp + 4 * t) = make_float4(0.f, 0.f, 0.f, 0.f);
  if (t < DEPTH * NQ) {
    int d = t / NQ, bit = t - d * NQ;
    float hg = 0.5f * theta[d * NQ + (13 - bit)];
    gtab[t] = make_float2(cosf(hg), sinf(hg));
  }
  if (t < 88) {
    int o, v; float s = 0.f;
    if (t < 32) { o = t >> 4; v = t & 15;
      #pragma unroll
      for (int i = 0; i < 4; ++i) s += ((v>>i)&1) ? -head_w[o*NQ+i] : head_w[o*NQ+i];
    } else if (t < 64) { o = (t-32) >> 4; v = t & 15;
      #pragma unroll
      for (int i = 0; i < 4; ++i) s += ((v>>i)&1) ? -head_w[o*NQ+8+i] : head_w[o*NQ+8+i];
    } else if (t < 72) { o = (t-64) >> 2; v = t & 3;
      s = ((v&1)?-head_w[o*NQ+4]:head_w[o*NQ+4]) + ((v&2)?-head_w[o*NQ+5]:head_w[o*NQ+5]);
    } else if (t < 80) { o = (t-72) >> 2; v = t & 3;
      s = ((v&1)?-head_w[o*NQ+6]:head_w[o*NQ+6]) + ((v&2)?-head_w[o*NQ+7]:head_w[o*NQ+7]);
    } else { o = (t-80) >> 2; v = t & 3;
      s = ((v&1)?-head_w[o*NQ+12]:head_w[o*NQ+12]) + ((v&2)?-head_w[o*NQ+13]:head_w[o*NQ+13]);
    }
    wtab[t] = s;
  }
  __syncthreads();
  // Bm: 24 x 16 x 16 (arithmetic = rounds 5-15, CZ signs baked)
  #pragma unroll
  for (int i = 0; i < 12; ++i) {
    int e = t + (i << 9);
    int pid = e >> 8, n = (e >> 4) & 15, k = e & 15;
    int d = pid >> 2, p = pid & 3;
    float val;
    if (p < 3) {
      val = 1.f;
      #pragma unroll
      for (int j = 0; j < 4; ++j) {
        float2 g = gtab[d * NQ + 4 * p + j];
        val *= ((n >> j) & 1) ? (((k >> j) & 1) ? g.x : g.y)
                              : (((k >> j) & 1) ? -g.y : g.x);
      }
      if (d >= 1) {
        int s = ((k & (k >> 1)) ^ ((k >> 1) & (k >> 2)) ^ ((k >> 2) & (k >> 3))) & 1;
        if (s) val = -val;
        if ((n & 1) && (k & 8)) val = -val;    // cross-pair CZ sign
      }
    } else {          // g3grp = [12,13,6,7]: G12 x G13 x I x I
      if ((((n ^ k) >> 2) & 3) != 0) val = 0.f;
      else {
        float2 gA = gtab[d * NQ + 12], gB = gtab[d * NQ + 13];
        float f0 = (n & 1) ? ((k & 1) ? gA.x : gA.y) : ((k & 1) ? -gA.y : gA.x);
        float f1 = ((n >> 1) & 1) ? (((k >> 1) & 1) ? gB.x : gB.y)
                                  : (((k >> 1) & 1) ? -gB.y : gB.x);
        val = f0 * f1;
        if (d >= 1 && (k & (k >> 1) & 1)) val = -val;    // intra pair (12,13)
      }
    }
    BmG[pid * 256 + n * 16 + k] = (h16)val;
  }
}

// ============ main kernel ============
// One block = one real component (comp=blockIdx&1) of item b=blockIdx>>1.
// Round-14 structure verbatim (single in-place buffer, LDS-staged init, paired
// x16-MFMA halves with D1->B2 register chaining, gates from d_ws per layer).
// ROUND-16: (a) revert r15's register-init (it spilled 50MB of scratch);
// (b) keep prep-folded memset; (c) targeted asm barriers: WAR = bare s_barrier,
// publish = lgkmcnt(0)+s_barrier -> no vmcnt drains, gate loads overlap compute.
__global__ __launch_bounds__(BLOCK, 8) void qsim_kernel(
    const float* __restrict__ x, const h16* __restrict__ BmG,
    const float* __restrict__ wtabG, const float* __restrict__ head_b,
    float* __restrict__ out)   // (512,2) zeroed by prep, accumulated atomically
{
  extern __shared__ __align__(16) char sbuf[];   // 33792 B state buffer (in-place)
  __shared__ float wtab[88];
  __shared__ float xc[NQ], xs[NQ];
  __shared__ float redbuf[16];

  const int t = threadIdx.x;
  const int b = blockIdx.x >> 1;
  const int comp = blockIdx.x & 1;
  const int lane = t & 63;
  const int w = t >> 6;        // 8 waves
  const int m = lane & 15;
  const int kg = lane >> 4;

  // ---- phase 0: load tables / per-item trig ----
  if (t < 88) wtab[t] = wtabG[t];
  if (t >= 128 && t < 128 + NQ) {
    int bit = t - 128;
    float h = 0.5f * x[b * NQ + (13 - bit)];
    xc[bit] = cosf(h); xs[bit] = sinf(h);
  }
  __syncthreads();

  // ---- init product state -> view X (E0 ordering, rounds 7-14) ----
  {
    float Mt = 1.f;
    #pragma unroll
    for (int p = 5; p < 14; ++p) Mt *= ((t >> (p - 5)) & 1) ? xs[p] : xc[p];
    const int pct = __popc((unsigned)t);
    uint32_t base = (uint32_t)(t >> 3) * TS + (uint32_t)((2 * t) & 15) * 32;
    #pragma unroll
    for (int g = 0; g < 4; ++g) {
      union { h16 h[8]; uint4 u; } pk;
      #pragma unroll
      for (int i = 0; i < 8; ++i) {
        int j = g * 8 + i;
        float mm = Mt;
        #pragma unroll
        for (int p = 0; p < 5; ++p) mm *= ((j >> p) & 1) ? xs[p] : xc[p];
        int e = (pct + __popc((unsigned)j)) & 3;   // (-i)^e
        float v = (comp == 0) ? ((e == 0) ? mm : ((e == 2) ? -mm : 0.f))
                              : ((e == 1) ? -mm : ((e == 3) ? mm : 0.f));
        pk.h[i] = (h16)v;
      }
      *(uint4*)(sbuf + base + (uint32_t)(g >> 1) * 32 + (uint32_t)(g & 1) * 16) = pk.u;
    }
  }
  __syncthreads();

  // A-fragment (16x16x16): lane reads row m, cols kg*4..kg*4+3 -> b64, ALL lanes
  const uint32_t raA = (uint32_t)w * (8 * TS) + (uint32_t)m * 32 + (uint32_t)kg * 8;
  const uint32_t raB = (uint32_t)((w & 1) * 8 + 16 * (w >> 1)) * TS
                     + (uint32_t)m * 32 + (uint32_t)kg * 8;
  const uint32_t wbase = (uint32_t)m * TS + ((uint32_t)(w >> 1) + 4u * (uint32_t)kg) * 32
                       + (uint32_t)((w & 1) * 16);

  float l0 = 0.f, l1 = 0.f;

  // paired half-layer: read, MFMA1(state,gB) -> MFMA2(gA, D1-as-B), write in-place.
  auto do_half = [&](uint32_t rbase, h4 gB, h4 gA, bool last) {
    h4 av[8];
    #pragma unroll
    for (int jt = 0; jt < 8; ++jt)
      av[jt] = *(const h4*)(sbuf + rbase + (uint32_t)jt * TS);
    uint32_t qk[8][2];
    float bs0 = 0.f, bs1 = 0.f;
    if (last) {
      bs0 = wtab[32 + m] + wtab[64 + (w >> 1)] + wtab[72 + kg];
      bs1 = wtab[48 + m] + wtab[68 + (w >> 1)] + wtab[76 + kg];
    }
    #pragma unroll
    for (int jt = 0; jt < 8; ++jt) {
      f4 acc = {0.f, 0.f, 0.f, 0.f};
      acc = __builtin_amdgcn_mfma_f32_16x16x16f16(av[jt], gB, acc, 0, 0, 0);
      union { h16 h[4]; h4 v; uint32_t d[2]; } c1;
      c1.h[0] = (h16)acc[0]; c1.h[1] = (h16)acc[1];
      c1.h[2] = (h16)acc[2]; c1.h[3] = (h16)acc[3];
      f4 acc2 = {0.f, 0.f, 0.f, 0.f};
      acc2 = __builtin_amdgcn_mfma_f32_16x16x16f16(gA, c1.v, acc2, 0, 0, 0);
      if (!last) {
        union { h16 h[4]; uint32_t d[2]; } c2;
        c2.h[0] = (h16)acc2[0]; c2.h[1] = (h16)acc2[1];
        c2.h[2] = (h16)acc2[2]; c2.h[3] = (h16)acc2[3];
        qk[jt][0] = c2.d[0]; qk[jt][1] = c2.d[1];
      } else {
        float wt0 = wtab[(w & 1) * 8 + jt], wt1 = wtab[16 + (w & 1) * 8 + jt];
        #pragma unroll
        for (int j = 0; j < 4; ++j) {
          float pr = acc2[j] * acc2[j];
          l0 += pr * (bs0 + wt0 + wtab[80 + j]);
          l1 += pr * (bs1 + wt1 + wtab[84 + j]);
        }
      }
    }
    if (!last) {
      BAR_WAR();    // all waves' reads of this view done (consumed pre-arrival);
                    // no waitcnt -> global gate loads stay in flight
      #pragma unroll
      for (int r = 0; r < 4; ++r) {
        uint32_t o[4];
        #pragma unroll
        for (int q = 0; q < 4; ++q) {
          uint32_t lo = qk[2 * q][r >> 1], hi = qk[2 * q + 1][r >> 1];
          o[q] = (r & 1) ? ((lo >> 16) | (hi & 0xffff0000u))
                         : ((lo & 0xffffu) | (hi << 16));
        }
        *(uint4*)(sbuf + wbase + (uint32_t)r * (16 * TS)) =
            make_uint4(o[0], o[1], o[2], o[3]);
      }
      BAR_PUB();    // drain LDS writes only (lgkmcnt), then barrier
    }
  };

  // gate fragments: loaded fresh at each layer top (L2-hot broadcast; short
  // live range -> no spill; loads overlap half-A compute thanks to BAR_WAR/PUB)
  const h16* fb = BmG + (m * 16 + kg * 4);

  #pragma unroll 1
  for (int d = 0; d < DEPTH; ++d) {
    const h16* nf = fb + d * 1024;
    h4 g0f = *(const h4*)(nf +   0);
    h4 g1f = *(const h4*)(nf + 256);
    h4 g2f = *(const h4*)(nf + 512);
    h4 g3f = *(const h4*)(nf + 768);
    do_half(raA, g0f, g1f, false);                 // passes 0,1 (g0 then g1)
    do_half(raB, g2f, g3f, d == DEPTH - 1);        // passes 2,3 (g2 then g3grp)
  }

  // ---- reduce partial logits, accumulate re/im via atomics ----
  #pragma unroll
  for (int off = 32; off > 0; off >>= 1) {
    l0 += __shfl_xor(l0, off);
    l1 += __shfl_xor(l1, off);
  }
  if (lane == 0) { redbuf[w] = l0; redbuf[8 + w] = l1; }
  __syncthreads();
  if (t == 0) {
    float s0 = 0.f, s1 = 0.f;
    #pragma unroll
    for (int i = 0; i < 8; ++i) { s0 += redbuf[i]; s1 += redbuf[8 + i]; }
    if (comp == 0) { s0 += head_b[0]; s1 += head_b[1]; }
    atomicAdd(&out[b * 2 + 0], s0);
    atomicAdd(&out[b * 2 + 1], s1);
  }
}

extern "C" void kernel_launch(void* const* d_in, const int* in_sizes, int n_in,
                              void* d_out, int out_size, void* d_ws, size_t ws_size,
                              hipStream_t stream) {
    const float* x      = (const float*)d_in[0];
    const float* theta  = (const float*)d_in[1];
    const float* head_w = (const float*)d_in[2];
    const float* head_b = (const float*)d_in[3];
    float* outp = (float*)d_out;
    h16*  BmG   = (h16*)d_ws;
    float* wtabG = (float*)((char*)d_ws + 12288);
    const int batch = in_sizes[0] / NQ;  // 512
    prep_kernel<<<1, 512, 0, stream>>>(theta, head_w, BmG, wtabG, outp);
    qsim_kernel<<<batch * 2, BLOCK, BUFSZ, stream>>>(x, BmG, wtabG, head_b, outp);
}